// Round 3
// baseline (571.471 us; speedup 1.0000x reference)
//
#include <hip/hip_runtime.h>
#include <math.h>

#define TOKENS 16384
#define C 1024
#define RH 256     // router hidden
#define E 32
#define D 32       // per-expert block dim
#define H 128      // expert hidden
#define NEL (E * H * D)   // 131072 elements per weight tensor
#define BCAP 8192         // bucket capacity per expert (avg load 2048; 4x headroom)
#define NCHUNK 16         // chunks per expert -> 512 expert blocks

// ---------------- Kernel 1a: partial |w| sums (deterministic per-block) ----------------
__global__ __launch_bounds__(256) void absum_kernel(
    const float* __restrict__ gate, const float* __restrict__ up,
    const float* __restrict__ down, double* __restrict__ partial) {
    const int which = blockIdx.y;
    const float* src = which == 0 ? gate : (which == 1 ? up : down);
    const float4* src4 = (const float4*)src;
    const int base4 = blockIdx.x * 1024;
    const int tid = threadIdx.x;
    double s = 0.0;
    #pragma unroll
    for (int v = 0; v < 4; ++v) {
        const float4 f = src4[base4 + tid + v * 256];
        s += (double)fabsf(f.x) + (double)fabsf(f.y) +
             (double)fabsf(f.z) + (double)fabsf(f.w);
    }
    __shared__ double red[256];
    red[tid] = s;
    __syncthreads();
    for (int off = 128; off > 0; off >>= 1) {
        if (tid < off) red[tid] += red[tid + off];
        __syncthreads();
    }
    if (tid == 0) partial[which * 32 + blockIdx.x] = red[0];
}

// ---------------- Kernel 1b: fold partials -> gamma[3]; zero bucket counts ----------------
__global__ void gamma_kernel(const double* __restrict__ partial,
                             float* __restrict__ gammaArr, int* __restrict__ counts) {
    const int t = threadIdx.x;
    if (t < 3) {
        double s = 0.0;
        for (int j = 0; j < 32; ++j) s += partial[t * 32 + j];
        gammaArr[t] = (float)(s / (double)NEL) + 1e-8f;
    }
    if (t >= 32) counts[t - 32] = 0;   // ws is poisoned 0xAA each launch
}

// ---------------- Kernel 1c: elementwise ternary quantize (layout preserved) ----------------
__global__ __launch_bounds__(256) void quant_all(
    const float* __restrict__ gate, const float* __restrict__ up,
    const float* __restrict__ down, const float* __restrict__ gammaArr,
    float* __restrict__ gQ, float* __restrict__ uQ, float* __restrict__ dQ) {
    const int idx4 = blockIdx.x * 256 + threadIdx.x;   // [0, 3*32768)
    const int which = idx4 >> 15;
    const int i4 = idx4 & 32767;
    const float4* s4 = (const float4*)(which == 0 ? gate : (which == 1 ? up : down));
    float4* o4 = (float4*)(which == 0 ? gQ : (which == 1 ? uQ : dQ));
    const float gam = gammaArr[which];
    float4 v = s4[i4];
    v.x = fminf(1.f, fmaxf(-1.f, rintf(v.x / gam))) * gam;
    v.y = fminf(1.f, fmaxf(-1.f, rintf(v.y / gam))) * gam;
    v.z = fminf(1.f, fmaxf(-1.f, rintf(v.z / gam))) * gam;
    v.w = fminf(1.f, fmaxf(-1.f, rintf(v.w / gam))) * gam;
    o4[i4] = v;
}

// ---------------- Kernel 2: H1 = silu(X @ W1^T), fp32, 8x8 per thread ----------------
// 128 threads, BM=128, BN=64, BK=32. grid (128,4) = 512 blocks (2/CU).
__global__ __launch_bounds__(128) void gemm1_silu(
    const float* __restrict__ X, const float* __restrict__ W1,
    float* __restrict__ H1) {
    __shared__ float As[32][132];   // k-major: conflict-free b128 reads (hot path)
    __shared__ float Bs[32][68];
    const int tid = threadIdx.x;
    const int row0 = blockIdx.x * 128;
    const int col0 = blockIdx.y * 64;
    const int tx = tid & 7;         // 8 cols
    const int ty = tid >> 3;        // 8 rows (16 groups)
    float acc[8][8] = {};
    for (int kt = 0; kt < C; kt += 32) {
        #pragma unroll
        for (int L = 0; L < 8; ++L) {   // A tile: 128x32 = 1024 float4
            const int f = tid + L * 128;
            const int r = f >> 3, kq = (f & 7) << 2;
            const float4 v = *(const float4*)&X[(long)(row0 + r) * C + kt + kq];
            As[kq + 0][r] = v.x; As[kq + 1][r] = v.y;
            As[kq + 2][r] = v.z; As[kq + 3][r] = v.w;
        }
        #pragma unroll
        for (int L = 0; L < 4; ++L) {   // B tile: 64x32 = 512 float4
            const int f = tid + L * 128;
            const int n = f >> 3, kq = (f & 7) << 2;
            const float4 v = *(const float4*)&W1[(long)(col0 + n) * C + kt + kq];
            Bs[kq + 0][n] = v.x; Bs[kq + 1][n] = v.y;
            Bs[kq + 2][n] = v.z; Bs[kq + 3][n] = v.w;
        }
        __syncthreads();
        #pragma unroll
        for (int kk = 0; kk < 32; ++kk) {
            const float4 a0 = *(const float4*)&As[kk][ty * 8];
            const float4 a1 = *(const float4*)&As[kk][ty * 8 + 4];
            const float4 b0 = *(const float4*)&Bs[kk][tx * 8];
            const float4 b1 = *(const float4*)&Bs[kk][tx * 8 + 4];
            const float av[8] = {a0.x, a0.y, a0.z, a0.w, a1.x, a1.y, a1.z, a1.w};
            const float bv[8] = {b0.x, b0.y, b0.z, b0.w, b1.x, b1.y, b1.z, b1.w};
            #pragma unroll
            for (int i = 0; i < 8; ++i)
                #pragma unroll
                for (int j = 0; j < 8; ++j)
                    acc[i][j] = fmaf(av[i], bv[j], acc[i][j]);
        }
        __syncthreads();
    }
    #pragma unroll
    for (int i = 0; i < 8; ++i) {
        const int r = row0 + ty * 8 + i;
        float4 o0, o1;
        float* p0 = &o0.x; float* p1 = &o1.x;
        #pragma unroll
        for (int j = 0; j < 4; ++j) {
            const float v0 = acc[i][j];
            const float v1 = acc[i][j + 4];
            p0[j] = v0 / (1.f + __expf(-v0));
            p1[j] = v1 / (1.f + __expf(-v1));
        }
        *(float4*)&H1[(long)r * RH + col0 + tx * 8]     = o0;
        *(float4*)&H1[(long)r * RH + col0 + tx * 8 + 4] = o1;
    }
}

// ---------------- Kernel 3: logits, top-4, weights + expert bucketing ----------------
__global__ __launch_bounds__(64) void router2_kernel(
    const float* __restrict__ H1, const float* __restrict__ W2,
    float* __restrict__ rw, int* __restrict__ counts, int* __restrict__ bucket) {
    __shared__ float w2s[RH][E + 1];
    const int tid = threadIdx.x;
    for (int i = tid; i < E * RH; i += 64) {
        const int e = i >> 8, h = i & 255;
        w2s[h][e] = W2[i];
    }
    __syncthreads();
    const int tok = blockIdx.x * 64 + tid;
    float l[E] = {};
    const float* hp = H1 + (long)tok * RH;
    for (int h = 0; h < RH; h += 4) {
        const float4 xv = *(const float4*)&hp[h];
        const float xs[4] = {xv.x, xv.y, xv.z, xv.w};
        #pragma unroll
        for (int q = 0; q < 4; ++q)
            #pragma unroll
            for (int e = 0; e < E; ++e)
                l[e] = fmaf(xs[q], w2s[h + q][e], l[e]);
    }
    unsigned chosen = 0u;
    float tv[4]; int ti[4];
    #pragma unroll
    for (int s = 0; s < 4; ++s) {
        float best = -1e30f; int bi = 0;
        #pragma unroll
        for (int e = 0; e < E; ++e) {
            const bool ok = (((chosen >> e) & 1u) == 0u) && (l[e] > best);
            best = ok ? l[e] : best;
            bi   = ok ? e    : bi;
        }
        chosen |= 1u << bi;
        tv[s] = best; ti[s] = bi;
    }
    const float m = tv[0];
    const float ev[4] = {__expf(tv[0] - m), __expf(tv[1] - m),
                         __expf(tv[2] - m), __expf(tv[3] - m)};
    const float inv = 1.f / (ev[0] + ev[1] + ev[2] + ev[3]);
    #pragma unroll
    for (int s = 0; s < 4; ++s) {
        rw[tok * 4 + s] = ev[s] * inv;
        const int pos = atomicAdd(&counts[ti[s]], 1);
        if (pos < BCAP) bucket[ti[s] * BCAP + pos] = tok * 4 + s;
    }
}

// ---------------- Kernel 4: zero output ----------------
__global__ void zero_kernel(float4* __restrict__ out, int n4) {
    int i = blockIdx.x * blockDim.x + threadIdx.x;
    const int stride = gridDim.x * blockDim.x;
    for (; i < n4; i += stride) out[i] = make_float4(0.f, 0.f, 0.f, 0.f);
}

// ---------------- Kernel 5: expert-major compute, weights in registers ----------------
// grid (32, NCHUNK), 256 threads. 2 tokens per iteration (128 threads each).
__global__ __launch_bounds__(256) void expert_compute(
    const float* __restrict__ X, const float* __restrict__ gQ,
    const float* __restrict__ uQ, const float* __restrict__ dQ,
    const int* __restrict__ counts, const int* __restrict__ bucket,
    const float* __restrict__ rw, float* __restrict__ out) {
    const int e = blockIdx.x;
    const int chunk = blockIdx.y;
    int n = counts[e]; if (n > BCAP) n = BCAP;
    const int per = (n + NCHUNK - 1) / NCHUNK;
    int start = chunk * per; if (start > n) start = n;
    int end = start + per;   if (end > n)   end = n;
    const int niter = (end - start + 1) >> 1;
    const int tid  = threadIdx.x;
    const int tg   = tid >> 7;           // token subgroup 0/1
    const int h    = tid & 127;          // gate/up output row
    const int d    = tid & 31;           // down output dim
    const int hseg = (tid >> 5) & 3;     // down h-segment
    // preload this expert's weights into registers (rows are contiguous)
    float greg[32], ureg[32], dreg[32];
    {
        const float4* gp = (const float4*)(gQ + (e << 12) + h * D);
        const float4* up = (const float4*)(uQ + (e << 12) + h * D);
        const float4* dp = (const float4*)(dQ + (e << 12) + d * H + hseg * 32);
        #pragma unroll
        for (int j = 0; j < 8; ++j) {
            float4 v = gp[j];
            greg[j*4+0]=v.x; greg[j*4+1]=v.y; greg[j*4+2]=v.z; greg[j*4+3]=v.w;
            v = up[j];
            ureg[j*4+0]=v.x; ureg[j*4+1]=v.y; ureg[j*4+2]=v.z; ureg[j*4+3]=v.w;
            v = dp[j];
            dreg[j*4+0]=v.x; dreg[j*4+1]=v.y; dreg[j*4+2]=v.z; dreg[j*4+3]=v.w;
        }
    }
    __shared__ float xs[2][32];
    __shared__ float hs[2][128];
    __shared__ float ps[2][4][32];
    for (int it = 0; it < niter; ++it) {
        const int i = start + it * 2 + tg;
        const bool act = i < end;
        int entry = 0;
        if (act) entry = bucket[e * BCAP + i];
        const int tok = entry >> 2;
        if (act && h < D) xs[tg][h] = X[(long)tok * C + e * D + h];
        __syncthreads();                                   // bar A
        if (act) {
            float g = 0.f, u = 0.f;
            #pragma unroll
            for (int j4 = 0; j4 < 8; ++j4) {
                const float4 xv = *(const float4*)&xs[tg][j4 * 4];
                g = fmaf(xv.x, greg[j4*4+0], g); g = fmaf(xv.y, greg[j4*4+1], g);
                g = fmaf(xv.z, greg[j4*4+2], g); g = fmaf(xv.w, greg[j4*4+3], g);
                u = fmaf(xv.x, ureg[j4*4+0], u); u = fmaf(xv.y, ureg[j4*4+1], u);
                u = fmaf(xv.z, ureg[j4*4+2], u); u = fmaf(xv.w, ureg[j4*4+3], u);
            }
            hs[tg][h] = g / (1.f + __expf(-g)) * u;        // silu(g)*u
        }
        __syncthreads();                                   // bar B
        if (act) {
            float p = 0.f;
            #pragma unroll
            for (int j4 = 0; j4 < 8; ++j4) {
                const float4 hv = *(const float4*)&hs[tg][hseg * 32 + j4 * 4];
                p = fmaf(hv.x, dreg[j4*4+0], p); p = fmaf(hv.y, dreg[j4*4+1], p);
                p = fmaf(hv.z, dreg[j4*4+2], p); p = fmaf(hv.w, dreg[j4*4+3], p);
            }
            ps[tg][hseg][d] = p;
        }
        __syncthreads();                                   // bar C
        if (act && hseg == 0) {
            const float tot = ps[tg][0][d] + ps[tg][1][d] + ps[tg][2][d] + ps[tg][3][d];
            out[(long)tok * C + e * D + d] = rw[entry] * tot;
        }
        // next iteration's bar A separates these reads from buffer reuse
    }
}

extern "C" void kernel_launch(void* const* d_in, const int* in_sizes, int n_in,
                              void* d_out, int out_size, void* d_ws, size_t ws_size,
                              hipStream_t stream) {
    const float* x  = (const float*)d_in[0];
    const float* w1 = (const float*)d_in[1];
    const float* w2 = (const float*)d_in[2];
    const float* gw = (const float*)d_in[3];
    const float* uw = (const float*)d_in[4];
    const float* dw = (const float*)d_in[5];
    float* out = (float*)d_out;

    char* ws = (char*)d_ws;
    float*  gQ    = (float*)(ws);                               // 512 KB
    float*  uQ    = (float*)(ws + (512 << 10));                 // 512 KB
    float*  dQ    = (float*)(ws + (1024 << 10));                // 512 KB
    float*  H1    = (float*)(ws + (1536 << 10));                // 16 MB
    size_t  off   = (1536 << 10) + (16 << 20);
    float*  rw    = (float*)(ws + off);                         // 256 KB
    double* part  = (double*)(ws + off + (256 << 10));          // 768 B
    float*  gamma = (float*) (ws + off + (256 << 10) + 1024);   // 12 B
    int*    counts= (int*)   (ws + off + (256 << 10) + 1280);   // 128 B
    int*    bucket= (int*)   (ws + off + (256 << 10) + 4096);   // 1 MB

    absum_kernel<<<dim3(32, 3), 256, 0, stream>>>(gw, uw, dw, part);
    gamma_kernel<<<1, 64, 0, stream>>>(part, gamma, counts);
    quant_all<<<3 * NEL / 1024, 256, 0, stream>>>(gw, uw, dw, gamma, gQ, uQ, dQ);
    gemm1_silu<<<dim3(TOKENS / 128, RH / 64), 128, 0, stream>>>(x, w1, H1);
    router2_kernel<<<TOKENS / 64, 64, 0, stream>>>(H1, w2, rw, counts, bucket);
    zero_kernel<<<4096, 256, 0, stream>>>((float4*)out, TOKENS * C / 4);
    expert_compute<<<dim3(E, NCHUNK), 256, 0, stream>>>(x, gQ, uQ, dQ, counts, bucket, rw, out);
}

// Round 4
// 365.639 us; speedup vs baseline: 1.5629x; 1.5629x over previous
//
#include <hip/hip_runtime.h>
#include <math.h>

#define TOKENS 16384
#define C 1024
#define RH 256     // router hidden
#define E 32
#define D 32       // per-expert block dim
#define H 128      // expert hidden
#define BM 128
#define BN 64
#define BK 32
#define NEL (E * H * D)   // 131072 elements per weight tensor
#define BCAP 8192         // bucket capacity per expert (avg load 2048)
#define NCHUNK 32         // chunks per expert -> 1024 expert blocks

// ---------------- Kernel 1a: partial |w| sums (deterministic per-block) ----------------
__global__ __launch_bounds__(256) void absum_kernel(
    const float* __restrict__ gate, const float* __restrict__ up,
    const float* __restrict__ down, double* __restrict__ partial) {
    const int which = blockIdx.y;
    const float* src = which == 0 ? gate : (which == 1 ? up : down);
    const float4* src4 = (const float4*)src;
    const int base4 = blockIdx.x * 1024;
    const int tid = threadIdx.x;
    double s = 0.0;
    #pragma unroll
    for (int v = 0; v < 4; ++v) {
        const float4 f = src4[base4 + tid + v * 256];
        s += (double)fabsf(f.x) + (double)fabsf(f.y) +
             (double)fabsf(f.z) + (double)fabsf(f.w);
    }
    __shared__ double red[256];
    red[tid] = s;
    __syncthreads();
    for (int off = 128; off > 0; off >>= 1) {
        if (tid < off) red[tid] += red[tid + off];
        __syncthreads();
    }
    if (tid == 0) partial[which * 32 + blockIdx.x] = red[0];
}

// ---------------- Kernel 1b: fold partials -> gamma[3]; zero bucket counts ----------------
__global__ void gamma_kernel(const double* __restrict__ partial,
                             float* __restrict__ gammaArr, int* __restrict__ counts) {
    const int t = threadIdx.x;
    if (t < 3) {
        double s = 0.0;
        for (int j = 0; j < 32; ++j) s += partial[t * 32 + j];
        gammaArr[t] = (float)(s / (double)NEL) + 1e-8f;
    }
    if (t >= 32) counts[(t - 32) * 16] = 0;   // padded counters (64B apart)
}

// ---------------- Kernel 1c: elementwise ternary quantize (layout preserved) ----------------
__global__ __launch_bounds__(256) void quant_all(
    const float* __restrict__ gate, const float* __restrict__ up,
    const float* __restrict__ down, const float* __restrict__ gammaArr,
    float* __restrict__ gQ, float* __restrict__ uQ, float* __restrict__ dQ) {
    const int idx4 = blockIdx.x * 256 + threadIdx.x;   // [0, 3*32768)
    const int which = idx4 >> 15;
    const int i4 = idx4 & 32767;
    const float4* s4 = (const float4*)(which == 0 ? gate : (which == 1 ? up : down));
    float4* o4 = (float4*)(which == 0 ? gQ : (which == 1 ? uQ : dQ));
    const float gam = gammaArr[which];
    float4 v = s4[i4];
    v.x = fminf(1.f, fmaxf(-1.f, rintf(v.x / gam))) * gam;
    v.y = fminf(1.f, fmaxf(-1.f, rintf(v.y / gam))) * gam;
    v.z = fminf(1.f, fmaxf(-1.f, rintf(v.z / gam))) * gam;
    v.w = fminf(1.f, fmaxf(-1.f, rintf(v.w / gam))) * gam;
    o4[i4] = v;
}

// ---------------- Kernel 2: H1 = silu(X @ W1^T) — round-2 proven config ----------------
__global__ __launch_bounds__(256) void gemm1_silu(
    const float* __restrict__ X, const float* __restrict__ W1,
    float* __restrict__ H1) {
    __shared__ float As[BK][BM + 4];
    __shared__ float Bs[BK][BN + 4];
    const int tid = threadIdx.x;
    const int row0 = blockIdx.x * BM;
    const int col0 = blockIdx.y * BN;
    const int tx = tid & 15;           // 4 cols each
    const int ty = tid >> 4;           // 8 rows each
    float acc[8][4] = {};
    for (int kt = 0; kt < C; kt += BK) {
        #pragma unroll
        for (int L = 0; L < 4; ++L) {      // A tile: 128x32
            const int f = tid + L * 256;
            const int r = f >> 3, kq = (f & 7) << 2;
            const float4 v = *(const float4*)&X[(long)(row0 + r) * C + kt + kq];
            As[kq + 0][r] = v.x; As[kq + 1][r] = v.y;
            As[kq + 2][r] = v.z; As[kq + 3][r] = v.w;
        }
        #pragma unroll
        for (int L = 0; L < 2; ++L) {      // B tile: 64x32
            const int f = tid + L * 256;
            const int n = f >> 3, kq = (f & 7) << 2;
            const float4 v = *(const float4*)&W1[(long)(col0 + n) * C + kt + kq];
            Bs[kq + 0][n] = v.x; Bs[kq + 1][n] = v.y;
            Bs[kq + 2][n] = v.z; Bs[kq + 3][n] = v.w;
        }
        __syncthreads();
        #pragma unroll
        for (int kk = 0; kk < BK; ++kk) {
            const float4 a0 = *(const float4*)&As[kk][ty * 8];
            const float4 a1 = *(const float4*)&As[kk][ty * 8 + 4];
            const float4 b  = *(const float4*)&Bs[kk][tx * 4];
            const float av[8] = {a0.x, a0.y, a0.z, a0.w, a1.x, a1.y, a1.z, a1.w};
            const float bv[4] = {b.x, b.y, b.z, b.w};
            #pragma unroll
            for (int i = 0; i < 8; ++i)
                #pragma unroll
                for (int j = 0; j < 4; ++j)
                    acc[i][j] = fmaf(av[i], bv[j], acc[i][j]);
        }
        __syncthreads();
    }
    #pragma unroll
    for (int i = 0; i < 8; ++i) {
        const int r = row0 + ty * 8 + i;
        float4 o;
        float* po = &o.x;
        #pragma unroll
        for (int j = 0; j < 4; ++j) {
            const float v = acc[i][j];
            po[j] = v / (1.f + __expf(-v));
        }
        *(float4*)&H1[(long)r * RH + col0 + tx * 4] = o;
    }
}

// ---------------- Kernel 3: router2 — 8 threads/token, LDS W2, shfl reduce ----------------
// grid 512 x 256 threads; 32 tokens/block.
__global__ __launch_bounds__(256) void router2_kernel(
    const float* __restrict__ H1, const float* __restrict__ W2,
    float* __restrict__ rw, int* __restrict__ counts, int* __restrict__ bucket) {
    // W2 staged as [e][8 chunks of 36 floats (32 data + 4 pad)] -> bank = 4e+4g+4q
    __shared__ __align__(16) float w2t[32 * 292];
    const int tid = threadIdx.x;
    for (int i = tid; i < E * RH; i += 256) {
        const int e = i >> 8, hh = i & 255;
        w2t[e * 292 + (hh >> 5) * 36 + (hh & 31)] = W2[i];
    }
    __syncthreads();
    const int tt = tid >> 3;       // token in block
    const int g  = tid & 7;        // 32-float h-chunk
    const int tok = blockIdx.x * 32 + tt;
    float4 xr[8];
    const float4* hp4 = (const float4*)(H1 + (long)tok * RH + g * 32);
    #pragma unroll
    for (int q = 0; q < 8; ++q) xr[q] = hp4[q];
    float l[E];
    #pragma unroll
    for (int e = 0; e < E; ++e) {
        const float4* wp = (const float4*)(w2t + e * 292 + g * 36);
        float acc = 0.f;
        #pragma unroll
        for (int q = 0; q < 8; ++q) {
            const float4 w = wp[q];
            acc = fmaf(xr[q].x, w.x, acc); acc = fmaf(xr[q].y, w.y, acc);
            acc = fmaf(xr[q].z, w.z, acc); acc = fmaf(xr[q].w, w.w, acc);
        }
        float v = acc;                       // reduce over g (lane bits 0..2)
        v += __shfl_xor(v, 1);
        v += __shfl_xor(v, 2);
        v += __shfl_xor(v, 4);
        l[e] = v;
    }
    if (g == 0) {
        unsigned chosen = 0u;
        float tv[4]; int ti[4];
        #pragma unroll
        for (int s = 0; s < 4; ++s) {
            float best = -1e30f; int bi = 0;
            #pragma unroll
            for (int e = 0; e < E; ++e) {
                const bool ok = (((chosen >> e) & 1u) == 0u) && (l[e] > best);
                best = ok ? l[e] : best;
                bi   = ok ? e    : bi;
            }
            chosen |= 1u << bi;
            tv[s] = best; ti[s] = bi;
        }
        const float m = tv[0];
        const float ev[4] = {__expf(tv[0] - m), __expf(tv[1] - m),
                             __expf(tv[2] - m), __expf(tv[3] - m)};
        const float inv = 1.f / (ev[0] + ev[1] + ev[2] + ev[3]);
        #pragma unroll
        for (int s = 0; s < 4; ++s) {
            rw[tok * 4 + s] = ev[s] * inv;
            const int pos = atomicAdd(&counts[ti[s] * 16], 1);
            if (pos < BCAP) bucket[ti[s] * BCAP + pos] = tok * 4 + s;
        }
    }
}

// ---------------- Kernel 4: zero output ----------------
__global__ void zero_kernel(float4* __restrict__ out, int n4) {
    int i = blockIdx.x * blockDim.x + threadIdx.x;
    const int stride = gridDim.x * blockDim.x;
    for (; i < n4; i += stride) out[i] = make_float4(0.f, 0.f, 0.f, 0.f);
}

// ---------------- Kernel 5: expert-major, 16 tokens/iter, weights in regs ----------------
// grid (32, 32), 256 threads.
__global__ __launch_bounds__(256) void expert_compute(
    const float* __restrict__ X, const float* __restrict__ gQ,
    const float* __restrict__ uQ, const float* __restrict__ dQ,
    const int* __restrict__ counts, const int* __restrict__ bucket,
    const float* __restrict__ rw, float* __restrict__ out) {
    const int e = blockIdx.x;
    const int chunk = blockIdx.y;
    int n = counts[e * 16]; if (n > BCAP) n = BCAP;
    const int per = (n + NCHUNK - 1) / NCHUNK;
    int start = chunk * per; if (start > n) start = n;
    int end = start + per;   if (end > n)   end = n;
    const int tid = threadIdx.x;
    // gate/up roles: row h, token half tg2
    const int h   = tid & 127;
    const int tg2 = tid >> 7;
    // down roles: d-pair, h-chunk hq, wave token-group tg
    const int dpair = tid & 15;
    const int hq    = (tid >> 4) & 3;
    const int tg    = tid >> 6;
    // ---- weight preload into registers ----
    float4 gr[8], ur[8];
    {
        const float4* gp = (const float4*)(gQ + (e << 12) + h * D);
        const float4* up = (const float4*)(uQ + (e << 12) + h * D);
        #pragma unroll
        for (int j = 0; j < 8; ++j) { gr[j] = gp[j]; ur[j] = up[j]; }
    }
    float4 dr0[8], dr1[8];
    {
        const float4* p0 = (const float4*)(dQ + (e << 12) + (dpair * 2) * H + hq * 32);
        const float4* p1 = (const float4*)(dQ + (e << 12) + (dpair * 2 + 1) * H + hq * 32);
        #pragma unroll
        for (int k = 0; k < 8; ++k) { dr0[k] = p0[k]; dr1[k] = p1[k]; }
    }
    __shared__ __align__(16) float xs[16][36];
    __shared__ __align__(16) float hsb[16][132];
    __shared__ int   tok_s[16];
    __shared__ float w_s[16];
    __shared__ int   act_s[16];
    const int niter = (end - start + 15) >> 4;
    for (int it = 0; it < niter; ++it) {
        const int base = start + it * 16;
        if (tid < 16) {
            const int idx = base + tid;
            const int a = idx < end;
            int entry = 0;
            if (a) entry = bucket[e * BCAP + idx];
            tok_s[tid] = a ? (entry >> 2) : 0;
            w_s[tid]   = a ? rw[entry] : 0.f;
            act_s[tid] = a;
        }
        __syncthreads();
        {   // stage x: 16 tokens x 32 floats, coalesced
            int i = tid;
            #pragma unroll
            for (int r2 = 0; r2 < 2; ++r2, i += 256) {
                const int t = i >> 5, d = i & 31;
                xs[t][d] = X[(long)tok_s[t] * C + e * D + d];
            }
        }
        __syncthreads();
        // ---- gate/up: tokens tg2*8..+7 at row h; broadcast xs reads ----
        {
            const int col = (h & ~31) | ((h + 8 * (h >> 5)) & 31);  // rotated store
            #pragma unroll
            for (int j = 0; j < 8; ++j) {
                const int t = tg2 * 8 + j;
                const float4* xv4 = (const float4*)&xs[t][0];
                float ga = 0.f, ua = 0.f;
                #pragma unroll
                for (int q = 0; q < 8; ++q) {
                    const float4 xv = xv4[q];
                    ga = fmaf(xv.x, gr[q].x, ga); ga = fmaf(xv.y, gr[q].y, ga);
                    ga = fmaf(xv.z, gr[q].z, ga); ga = fmaf(xv.w, gr[q].w, ga);
                    ua = fmaf(xv.x, ur[q].x, ua); ua = fmaf(xv.y, ur[q].y, ua);
                    ua = fmaf(xv.z, ur[q].z, ua); ua = fmaf(xv.w, ur[q].w, ua);
                }
                hsb[t][col] = ga / (1.f + __expf(-ga)) * ua;
            }
        }
        __syncthreads();
        // ---- down: tokens tg*4..+3, rows d0,d0+1, chunk hq; shfl-reduce ----
        #pragma unroll
        for (int j = 0; j < 4; ++j) {
            const int t = tg * 4 + j;
            float p0 = 0.f, p1 = 0.f;
            #pragma unroll
            for (int k = 0; k < 8; ++k) {
                const int cb = hq * 32 + ((4 * k + 8 * hq) & 31);   // rotated read
                const float4 hv = *(const float4*)&hsb[t][cb];
                p0 = fmaf(hv.x, dr0[k].x, p0); p0 = fmaf(hv.y, dr0[k].y, p0);
                p0 = fmaf(hv.z, dr0[k].z, p0); p0 = fmaf(hv.w, dr0[k].w, p0);
                p1 = fmaf(hv.x, dr1[k].x, p1); p1 = fmaf(hv.y, dr1[k].y, p1);
                p1 = fmaf(hv.z, dr1[k].z, p1); p1 = fmaf(hv.w, dr1[k].w, p1);
            }
            p0 += __shfl_xor(p0, 16); p0 += __shfl_xor(p0, 32);
            p1 += __shfl_xor(p1, 16); p1 += __shfl_xor(p1, 32);
            if (hq == 0 && act_s[t]) {
                const float wt = w_s[t];
                float2 o = make_float2(wt * p0, wt * p1);
                *(float2*)&out[(long)tok_s[t] * C + e * D + dpair * 2] = o;
            }
        }
        __syncthreads();
    }
}

extern "C" void kernel_launch(void* const* d_in, const int* in_sizes, int n_in,
                              void* d_out, int out_size, void* d_ws, size_t ws_size,
                              hipStream_t stream) {
    const float* x  = (const float*)d_in[0];
    const float* w1 = (const float*)d_in[1];
    const float* w2 = (const float*)d_in[2];
    const float* gw = (const float*)d_in[3];
    const float* uw = (const float*)d_in[4];
    const float* dw = (const float*)d_in[5];
    float* out = (float*)d_out;

    char* ws = (char*)d_ws;
    float*  gQ    = (float*)(ws);                               // 512 KB
    float*  uQ    = (float*)(ws + (512 << 10));                 // 512 KB
    float*  dQ    = (float*)(ws + (1024 << 10));                // 512 KB
    float*  H1    = (float*)(ws + (1536 << 10));                // 16 MB
    const size_t off = (1536 << 10) + (16 << 20);
    float*  rw    = (float*)(ws + off);                         // 256 KB
    double* part  = (double*)(ws + off + (256 << 10));          // 768 B
    float*  gamma = (float*) (ws + off + (256 << 10) + 1024);   // 12 B
    int*    counts= (int*)   (ws + off + (256 << 10) + 2048);   // 2 KB (padded)
    int*    bucket= (int*)   (ws + off + (256 << 10) + 8192);   // 1 MB

    absum_kernel<<<dim3(32, 3), 256, 0, stream>>>(gw, uw, dw, part);
    gamma_kernel<<<1, 64, 0, stream>>>(part, gamma, counts);
    quant_all<<<3 * NEL / 1024, 256, 0, stream>>>(gw, uw, dw, gamma, gQ, uQ, dQ);
    gemm1_silu<<<dim3(TOKENS / BM, RH / BN), 256, 0, stream>>>(x, w1, H1);
    router2_kernel<<<TOKENS / 32, 256, 0, stream>>>(H1, w2, rw, counts, bucket);
    zero_kernel<<<4096, 256, 0, stream>>>((float4*)out, TOKENS * C / 4);
    expert_compute<<<dim3(E, NCHUNK), 256, 0, stream>>>(x, gQ, uQ, dQ, counts, bucket, rw, out);
}

// Round 6
// 259.247 us; speedup vs baseline: 2.2043x; 1.4104x over previous
//
#include <hip/hip_runtime.h>
#include <math.h>

#define TOKENS 16384
#define C 1024
#define RH 256     // router hidden
#define E 32
#define D 32       // per-expert block dim
#define H 128      // expert hidden
#define NEL (E * H * D)   // 131072 elements per weight tensor
#define BCAP 8192         // bucket capacity per expert (avg load 2048)
#define NCHUNK 32         // chunks per expert -> 1024 expert blocks

typedef _Float16 f16x4 __attribute__((ext_vector_type(4)));
typedef _Float16 f16x8 __attribute__((ext_vector_type(8)));
typedef float    f32x4 __attribute__((ext_vector_type(4)));

// ---------------- Kernel 1a: partial |w| sums (deterministic per-block) ----------------
__global__ __launch_bounds__(256) void absum_kernel(
    const float* __restrict__ gate, const float* __restrict__ up,
    const float* __restrict__ down, double* __restrict__ partial) {
    const int which = blockIdx.y;
    const float* src = which == 0 ? gate : (which == 1 ? up : down);
    const float4* src4 = (const float4*)src;
    const int base4 = blockIdx.x * 1024;
    const int tid = threadIdx.x;
    double s = 0.0;
    #pragma unroll
    for (int v = 0; v < 4; ++v) {
        const float4 f = src4[base4 + tid + v * 256];
        s += (double)fabsf(f.x) + (double)fabsf(f.y) +
             (double)fabsf(f.z) + (double)fabsf(f.w);
    }
    __shared__ double red[256];
    red[tid] = s;
    __syncthreads();
    for (int off = 128; off > 0; off >>= 1) {
        if (tid < off) red[tid] += red[tid + off];
        __syncthreads();
    }
    if (tid == 0) partial[which * 32 + blockIdx.x] = red[0];
}

// ---------------- Kernel 1b: fold partials -> gamma[3]; zero bucket counts ----------------
__global__ void gamma_kernel(const double* __restrict__ partial,
                             float* __restrict__ gammaArr, int* __restrict__ counts) {
    const int t = threadIdx.x;
    if (t < 3) {
        double s = 0.0;
        for (int j = 0; j < 32; ++j) s += partial[t * 32 + j];
        gammaArr[t] = (float)(s / (double)NEL) + 1e-8f;
    }
    if (t >= 32) counts[(t - 32) * 16] = 0;   // padded counters (64B apart)
}

// ---------------- Kernel 1c: elementwise ternary quantize (layout preserved) ----------------
__global__ __launch_bounds__(256) void quant_all(
    const float* __restrict__ gate, const float* __restrict__ up,
    const float* __restrict__ down, const float* __restrict__ gammaArr,
    float* __restrict__ gQ, float* __restrict__ uQ, float* __restrict__ dQ) {
    const int idx4 = blockIdx.x * 256 + threadIdx.x;   // [0, 3*32768)
    const int which = idx4 >> 15;
    const int i4 = idx4 & 32767;
    const float4* s4 = (const float4*)(which == 0 ? gate : (which == 1 ? up : down));
    float4* o4 = (float4*)(which == 0 ? gQ : (which == 1 ? uQ : dQ));
    const float gam = gammaArr[which];
    float4 v = s4[i4];
    v.x = fminf(1.f, fmaxf(-1.f, rintf(v.x / gam))) * gam;
    v.y = fminf(1.f, fmaxf(-1.f, rintf(v.y / gam))) * gam;
    v.z = fminf(1.f, fmaxf(-1.f, rintf(v.z / gam))) * gam;
    v.w = fminf(1.f, fmaxf(-1.f, rintf(v.w / gam))) * gam;
    o4[i4] = v;
}

// ---------------- Kernel 2: H1 = silu(X @ W1^T) via fp16-split MFMA ----------------
// Exact split: x = xh + xl/2048 (xh=f16(x), xl=f16((x-xh)*2048)).
// X@W = Xh@Wh + (Xh@Wl + Xl@Wh)/2048 + O(2^-22).
// Block 256 thr (4 waves, 2x2), tile 128m x 64n, BK=32. LDS 24KB swizzled.
__global__ __launch_bounds__(256) void gemm1_mfma(
    const float* __restrict__ X, const float* __restrict__ W1,
    float* __restrict__ H1) {
    __shared__ __align__(16) _Float16 smem[12288];  // Ah 0, Al 4096, Bh 8192, Bl 10240
    const int tid  = threadIdx.x;
    const int lane = tid & 63;
    const int wid  = tid >> 6;
    const int row0 = blockIdx.x * 128;
    const int col0 = blockIdx.y * 64;
    const int wm = (wid >> 1) * 64;
    const int wn = (wid & 1) * 32;
    const int lr = lane & 15, q = lane >> 4;

    // ---- staging chunk map: 6 x 16B-fp32 chunks per thread ----
    const float* gsrc[6];
    int wh_[6], wl_[6];
    #pragma unroll
    for (int c = 0; c < 6; ++c) {
        const int id = c * 256 + tid;
        int row, c4, base;
        if (id < 1024) { row = id >> 3; c4 = id & 7; base = 0;
                         gsrc[c] = X  + (long)(row0 + row) * C + c4 * 4; }
        else { const int j = id - 1024; row = j >> 3; c4 = j & 7; base = 8192;
               gsrc[c] = W1 + (long)(col0 + row) * C + c4 * 4; }
        const int s  = (row ^ (row >> 2)) & 3;
        const int kb = c4 >> 1;
        wh_[c] = base + row * 32 + ((kb ^ s) << 3) + (c4 & 1) * 4;
        wl_[c] = wh_[c] + (base ? 2048 : 4096);
    }
    // ---- fragment read addresses (constant across k-tiles) ----
    int aA[4], aB[2];
    #pragma unroll
    for (int f = 0; f < 4; ++f) {
        const int row = wm + f * 16 + lr;
        const int s = (row ^ (row >> 2)) & 3;
        aA[f] = row * 32 + ((q ^ s) << 3);
    }
    #pragma unroll
    for (int g = 0; g < 2; ++g) {
        const int n = wn + g * 16 + lr;
        const int s = (n ^ (n >> 2)) & 3;
        aB[g] = 8192 + n * 32 + ((q ^ s) << 3);
    }

    f32x4 acc0[4][2] = {}, acc1[4][2] = {};
    float4 va[6], vb[6];

#define LOADG(V, KT) { _Pragma("unroll") \
    for (int c = 0; c < 6; ++c) V[c] = *(const float4*)(gsrc[c] + (KT)); }

#define STAGE(V) { _Pragma("unroll") \
    for (int c = 0; c < 6; ++c) { \
        const float4 v = V[c]; f16x4 hv, lv; \
        hv[0] = (_Float16)v.x; lv[0] = (_Float16)((v.x - (float)hv[0]) * 2048.f); \
        hv[1] = (_Float16)v.y; lv[1] = (_Float16)((v.y - (float)hv[1]) * 2048.f); \
        hv[2] = (_Float16)v.z; lv[2] = (_Float16)((v.z - (float)hv[2]) * 2048.f); \
        hv[3] = (_Float16)v.w; lv[3] = (_Float16)((v.w - (float)hv[3]) * 2048.f); \
        *(f16x4*)&smem[wh_[c]] = hv; \
        *(f16x4*)&smem[wl_[c]] = lv; } }

#define COMPUTE() { \
    f16x8 bh0 = *(const f16x8*)&smem[aB[0]]; \
    f16x8 bl0 = *(const f16x8*)&smem[aB[0] + 2048]; \
    f16x8 bh1 = *(const f16x8*)&smem[aB[1]]; \
    f16x8 bl1 = *(const f16x8*)&smem[aB[1] + 2048]; \
    _Pragma("unroll") \
    for (int f = 0; f < 4; ++f) { \
        const f16x8 ah = *(const f16x8*)&smem[aA[f]]; \
        const f16x8 al = *(const f16x8*)&smem[aA[f] + 4096]; \
        acc0[f][0] = __builtin_amdgcn_mfma_f32_16x16x32_f16(ah, bh0, acc0[f][0], 0, 0, 0); \
        acc1[f][0] = __builtin_amdgcn_mfma_f32_16x16x32_f16(ah, bl0, acc1[f][0], 0, 0, 0); \
        acc1[f][0] = __builtin_amdgcn_mfma_f32_16x16x32_f16(al, bh0, acc1[f][0], 0, 0, 0); \
        acc0[f][1] = __builtin_amdgcn_mfma_f32_16x16x32_f16(ah, bh1, acc0[f][1], 0, 0, 0); \
        acc1[f][1] = __builtin_amdgcn_mfma_f32_16x16x32_f16(ah, bl1, acc1[f][1], 0, 0, 0); \
        acc1[f][1] = __builtin_amdgcn_mfma_f32_16x16x32_f16(al, bh1, acc1[f][1], 0, 0, 0); \
    } }

    LOADG(va, 0);
    for (int kt = 0; kt < C; kt += 64) {
        STAGE(va);
        LOADG(vb, kt + 32);
        __syncthreads();
        COMPUTE();
        __syncthreads();
        STAGE(vb);
        if (kt + 64 < C) LOADG(va, kt + 64);
        __syncthreads();
        COMPUTE();
        __syncthreads();
    }
    // epilogue: combine scaled accumulators, silu, store
    const int crow = (lane >> 4) * 4, ccol = lane & 15;
    #pragma unroll
    for (int f = 0; f < 4; ++f)
        #pragma unroll
        for (int g = 0; g < 2; ++g)
            #pragma unroll
            for (int r = 0; r < 4; ++r) {
                const int m = row0 + wm + f * 16 + crow + r;
                const int n = col0 + wn + g * 16 + ccol;
                const float v = acc0[f][g][r] + acc1[f][g][r] * 4.8828125e-4f;
                H1[(long)m * RH + n] = v / (1.f + __expf(-v));
            }
#undef LOADG
#undef STAGE
#undef COMPUTE
}

// ---------------- Kernel 3: router2 — 8 thr/token + block-aggregated bucketing ----------------
__global__ __launch_bounds__(256) void router2_kernel(
    const float* __restrict__ H1, const float* __restrict__ W2,
    float* __restrict__ rw, int* __restrict__ counts, int* __restrict__ bucket) {
    __shared__ __align__(16) float w2t[32 * 292];
    __shared__ int lcnt[32];
    __shared__ int gbase[32];
    const int tid = threadIdx.x;
    for (int i = tid; i < E * RH; i += 256) {
        const int e = i >> 8, hh = i & 255;
        w2t[e * 292 + (hh >> 5) * 36 + (hh & 31)] = W2[i];
    }
    if (tid < 32) lcnt[tid] = 0;
    __syncthreads();
    const int tt = tid >> 3;       // token in block
    const int g  = tid & 7;        // 32-float h-chunk
    const int tok = blockIdx.x * 32 + tt;
    float4 xr[8];
    const float4* hp4 = (const float4*)(H1 + (long)tok * RH + g * 32);
    #pragma unroll
    for (int q = 0; q < 8; ++q) xr[q] = hp4[q];
    float l[E];
    #pragma unroll
    for (int e = 0; e < E; ++e) {
        const float4* wp = (const float4*)(w2t + e * 292 + g * 36);
        float acc = 0.f;
        #pragma unroll
        for (int q = 0; q < 8; ++q) {
            const float4 w = wp[q];
            acc = fmaf(xr[q].x, w.x, acc); acc = fmaf(xr[q].y, w.y, acc);
            acc = fmaf(xr[q].z, w.z, acc); acc = fmaf(xr[q].w, w.w, acc);
        }
        float v = acc;
        v += __shfl_xor(v, 1);
        v += __shfl_xor(v, 2);
        v += __shfl_xor(v, 4);
        l[e] = v;
    }
    int ti[4], lr_[4];
    if (g == 0) {
        unsigned chosen = 0u;
        float tv[4];
        #pragma unroll
        for (int s = 0; s < 4; ++s) {
            float best = -1e30f; int bi = 0;
            #pragma unroll
            for (int e = 0; e < E; ++e) {
                const bool ok = (((chosen >> e) & 1u) == 0u) && (l[e] > best);
                best = ok ? l[e] : best;
                bi   = ok ? e    : bi;
            }
            chosen |= 1u << bi;
            tv[s] = best; ti[s] = bi;
        }
        const float m = tv[0];
        const float ev[4] = {__expf(tv[0] - m), __expf(tv[1] - m),
                             __expf(tv[2] - m), __expf(tv[3] - m)};
        const float inv = 1.f / (ev[0] + ev[1] + ev[2] + ev[3]);
        #pragma unroll
        for (int s = 0; s < 4; ++s) {
            rw[tok * 4 + s] = ev[s] * inv;
            lr_[s] = atomicAdd(&lcnt[ti[s]], 1);    // LDS atomic, cheap
        }
    }
    __syncthreads();
    if (tid < 32) {
        const int c = lcnt[tid];
        gbase[tid] = c ? atomicAdd(&counts[tid * 16], c) : 0;  // 32 global atomics/block
    }
    __syncthreads();
    if (g == 0) {
        #pragma unroll
        for (int s = 0; s < 4; ++s)
            bucket[ti[s] * BCAP + gbase[ti[s]] + lr_[s]] = tok * 4 + s;
    }
}

// ---------------- Kernel 4: zero output ----------------
__global__ void zero_kernel(float4* __restrict__ out, int n4) {
    int i = blockIdx.x * blockDim.x + threadIdx.x;
    const int stride = gridDim.x * blockDim.x;
    for (; i < n4; i += stride) out[i] = make_float4(0.f, 0.f, 0.f, 0.f);
}

// ---------------- Kernel 5: expert-major, 16 tokens/iter, weights in regs ----------------
__global__ __launch_bounds__(256) void expert_compute(
    const float* __restrict__ X, const float* __restrict__ gQ,
    const float* __restrict__ uQ, const float* __restrict__ dQ,
    const int* __restrict__ counts, const int* __restrict__ bucket,
    const float* __restrict__ rw, float* __restrict__ out) {
    const int e = blockIdx.x;
    const int chunk = blockIdx.y;
    int n = counts[e * 16]; if (n > BCAP) n = BCAP;
    const int per = (n + NCHUNK - 1) / NCHUNK;
    int start = chunk * per; if (start > n) start = n;
    int end = start + per;   if (end > n)   end = n;
    const int tid = threadIdx.x;
    const int h   = tid & 127;
    const int tg2 = tid >> 7;
    const int dpair = tid & 15;
    const int hq    = (tid >> 4) & 3;
    const int tg    = tid >> 6;
    float4 gr[8], ur[8];
    {
        const float4* gp = (const float4*)(gQ + (e << 12) + h * D);
        const float4* up = (const float4*)(uQ + (e << 12) + h * D);
        #pragma unroll
        for (int j = 0; j < 8; ++j) { gr[j] = gp[j]; ur[j] = up[j]; }
    }
    float4 dr0[8], dr1[8];
    {
        const float4* p0 = (const float4*)(dQ + (e << 12) + (dpair * 2) * H + hq * 32);
        const float4* p1 = (const float4*)(dQ + (e << 12) + (dpair * 2 + 1) * H + hq * 32);
        #pragma unroll
        for (int k = 0; k < 8; ++k) { dr0[k] = p0[k]; dr1[k] = p1[k]; }
    }
    __shared__ __align__(16) float xs[16][36];
    __shared__ __align__(16) float hsb[16][132];
    __shared__ int   tok_s[16];
    __shared__ float w_s[16];
    __shared__ int   act_s[16];
    const int niter = (end - start + 15) >> 4;
    for (int it = 0; it < niter; ++it) {
        const int base = start + it * 16;
        if (tid < 16) {
            const int idx = base + tid;
            const int a = idx < end;
            int entry = 0;
            if (a) entry = bucket[e * BCAP + idx];
            tok_s[tid] = a ? (entry >> 2) : 0;
            w_s[tid]   = a ? rw[entry] : 0.f;
            act_s[tid] = a;
        }
        __syncthreads();
        {
            int i = tid;
            #pragma unroll
            for (int r2 = 0; r2 < 2; ++r2, i += 256) {
                const int t = i >> 5, d = i & 31;
                xs[t][d] = X[(long)tok_s[t] * C + e * D + d];
            }
        }
        __syncthreads();
        {
            const int col = (h & ~31) | ((h + 8 * (h >> 5)) & 31);
            #pragma unroll
            for (int j = 0; j < 8; ++j) {
                const int t = tg2 * 8 + j;
                const float4* xv4 = (const float4*)&xs[t][0];
                float ga = 0.f, ua = 0.f;
                #pragma unroll
                for (int q = 0; q < 8; ++q) {
                    const float4 xv = xv4[q];
                    ga = fmaf(xv.x, gr[q].x, ga); ga = fmaf(xv.y, gr[q].y, ga);
                    ga = fmaf(xv.z, gr[q].z, ga); ga = fmaf(xv.w, gr[q].w, ga);
                    ua = fmaf(xv.x, ur[q].x, ua); ua = fmaf(xv.y, ur[q].y, ua);
                    ua = fmaf(xv.z, ur[q].z, ua); ua = fmaf(xv.w, ur[q].w, ua);
                }
                hsb[t][col] = ga / (1.f + __expf(-ga)) * ua;
            }
        }
        __syncthreads();
        #pragma unroll
        for (int j = 0; j < 4; ++j) {
            const int t = tg * 4 + j;
            float p0 = 0.f, p1 = 0.f;
            #pragma unroll
            for (int k = 0; k < 8; ++k) {
                const int cb = hq * 32 + ((4 * k + 8 * hq) & 31);
                const float4 hv = *(const float4*)&hsb[t][cb];
                p0 = fmaf(hv.x, dr0[k].x, p0); p0 = fmaf(hv.y, dr0[k].y, p0);
                p0 = fmaf(hv.z, dr0[k].z, p0); p0 = fmaf(hv.w, dr0[k].w, p0);
                p1 = fmaf(hv.x, dr1[k].x, p1); p1 = fmaf(hv.y, dr1[k].y, p1);
                p1 = fmaf(hv.z, dr1[k].z, p1); p1 = fmaf(hv.w, dr1[k].w, p1);
            }
            p0 += __shfl_xor(p0, 16); p0 += __shfl_xor(p0, 32);
            p1 += __shfl_xor(p1, 16); p1 += __shfl_xor(p1, 32);
            if (hq == 0 && act_s[t]) {
                const float wt = w_s[t];
                float2 o = make_float2(wt * p0, wt * p1);
                *(float2*)&out[(long)tok_s[t] * C + e * D + dpair * 2] = o;
            }
        }
        __syncthreads();
    }
}

extern "C" void kernel_launch(void* const* d_in, const int* in_sizes, int n_in,
                              void* d_out, int out_size, void* d_ws, size_t ws_size,
                              hipStream_t stream) {
    const float* x  = (const float*)d_in[0];
    const float* w1 = (const float*)d_in[1];
    const float* w2 = (const float*)d_in[2];
    const float* gw = (const float*)d_in[3];
    const float* uw = (const float*)d_in[4];
    const float* dw = (const float*)d_in[5];
    float* out = (float*)d_out;

    char* ws = (char*)d_ws;
    float*  gQ    = (float*)(ws);                               // 512 KB
    float*  uQ    = (float*)(ws + (512 << 10));                 // 512 KB
    float*  dQ    = (float*)(ws + (1024 << 10));                // 512 KB
    float*  H1    = (float*)(ws + (1536 << 10));                // 16 MB
    const size_t off = (1536 << 10) + (16 << 20);
    float*  rw    = (float*)(ws + off);                         // 256 KB
    double* part  = (double*)(ws + off + (256 << 10));          // 768 B
    float*  gamma = (float*) (ws + off + (256 << 10) + 1024);   // 12 B
    int*    counts= (int*)   (ws + off + (256 << 10) + 2048);   // 2 KB (padded)
    int*    bucket= (int*)   (ws + off + (256 << 10) + 8192);   // 1 MB

    absum_kernel<<<dim3(32, 3), 256, 0, stream>>>(gw, uw, dw, part);
    gamma_kernel<<<1, 64, 0, stream>>>(part, gamma, counts);
    quant_all<<<3 * NEL / 1024, 256, 0, stream>>>(gw, uw, dw, gamma, gQ, uQ, dQ);
    gemm1_mfma<<<dim3(TOKENS / 128, RH / 64), 256, 0, stream>>>(x, w1, H1);
    router2_kernel<<<TOKENS / 32, 256, 0, stream>>>(H1, w2, rw, counts, bucket);
    zero_kernel<<<4096, 256, 0, stream>>>((float4*)out, TOKENS * C / 4);
    expert_compute<<<dim3(E, NCHUNK), 256, 0, stream>>>(x, gQ, uQ, dQ, counts, bucket, rw, out);
}

// Round 7
// 238.355 us; speedup vs baseline: 2.3976x; 1.0877x over previous
//
#include <hip/hip_runtime.h>
#include <math.h>

#define TOKENS 16384
#define C 1024
#define RH 256     // router hidden
#define E 32
#define D 32       // per-expert block dim
#define H 128      // expert hidden
#define NEL (E * H * D)   // 131072 elements per weight tensor
#define INV2048 4.8828125e-4f

typedef _Float16 f16x4 __attribute__((ext_vector_type(4)));
typedef _Float16 f16x8 __attribute__((ext_vector_type(8)));
typedef float    f32x4 __attribute__((ext_vector_type(4)));

// ---------------- Kernel 1a: partial |w| sums (deterministic per-block) ----------------
__global__ __launch_bounds__(256) void absum_kernel(
    const float* __restrict__ gate, const float* __restrict__ up,
    const float* __restrict__ down, double* __restrict__ partial) {
    const int which = blockIdx.y;
    const float* src = which == 0 ? gate : (which == 1 ? up : down);
    const float4* src4 = (const float4*)src;
    const int base4 = blockIdx.x * 1024;
    const int tid = threadIdx.x;
    double s = 0.0;
    #pragma unroll
    for (int v = 0; v < 4; ++v) {
        const float4 f = src4[base4 + tid + v * 256];
        s += (double)fabsf(f.x) + (double)fabsf(f.y) +
             (double)fabsf(f.z) + (double)fabsf(f.w);
    }
    __shared__ double red[256];
    red[tid] = s;
    __syncthreads();
    for (int off = 128; off > 0; off >>= 1) {
        if (tid < off) red[tid] += red[tid + off];
        __syncthreads();
    }
    if (tid == 0) partial[which * 32 + blockIdx.x] = red[0];
}

// ---------------- Kernel 1b: fold partials -> gamma[3] ----------------
__global__ void gamma_kernel(const double* __restrict__ partial,
                             float* __restrict__ gammaArr) {
    const int t = threadIdx.x;
    if (t < 3) {
        double s = 0.0;
        for (int j = 0; j < 32; ++j) s += partial[t * 32 + j];
        gammaArr[t] = (float)(s / (double)NEL) + 1e-8f;
    }
}

// ---------------- Kernel 1c: ternarize to f16 {-1,0,+1}; down pre-gathered to frag layout --
// blocks 0-63: gate -> gf [E][128][32];  64-127: up -> uf;  128-191: down -> dF frags.
// dF[e][f][lane][j] = tern(down[e][ d = (f>>2)*16 + (lane&15) ][ h = (f&3)*32 + (lane>>4)*8 + j ])
__global__ __launch_bounds__(256) void tern_prep(
    const float* __restrict__ gate, const float* __restrict__ up,
    const float* __restrict__ down, const float* __restrict__ gammaArr,
    _Float16* __restrict__ gf, _Float16* __restrict__ uf, _Float16* __restrict__ dF) {
    const int b = blockIdx.x;              // 0..191
    const int which = b >> 6;
    const int o = (b & 63) * 2048 + threadIdx.x * 8;
    const float gam = gammaArr[which];
    const float* src;
    _Float16* dst;
    if (which == 0)      { src = gate + o; dst = gf + o; }
    else if (which == 1) { src = up + o;   dst = uf + o; }
    else {
        const int e = o >> 12, f = (o >> 9) & 7, l = (o >> 3) & 63;
        const int d  = (f >> 2) * 16 + (l & 15);
        const int h0 = (f & 3) * 32 + (l >> 4) * 8;
        src = down + e * 4096 + d * 128 + h0;
        dst = dF + o;
    }
    const float4 v0 = *(const float4*)src;
    const float4 v1 = *(const float4*)(src + 4);
    const float a[8] = {v0.x, v0.y, v0.z, v0.w, v1.x, v1.y, v1.z, v1.w};
    f16x8 t;
    #pragma unroll
    for (int j = 0; j < 8; ++j)
        t[j] = (_Float16)fminf(1.f, fmaxf(-1.f, rintf(a[j] / gam)));
    *(f16x8*)dst = t;
}

// ---------------- Kernel 2: H1 = silu(X @ W1^T) via fp16-split MFMA (r6, passed) -------
__global__ __launch_bounds__(256) void gemm1_mfma(
    const float* __restrict__ X, const float* __restrict__ W1,
    float* __restrict__ H1) {
    __shared__ __align__(16) _Float16 smem[12288];  // Ah 0, Al 4096, Bh 8192, Bl 10240
    const int tid  = threadIdx.x;
    const int lane = tid & 63;
    const int wid  = tid >> 6;
    const int row0 = blockIdx.x * 128;
    const int col0 = blockIdx.y * 64;
    const int wm = (wid >> 1) * 64;
    const int wn = (wid & 1) * 32;
    const int lr = lane & 15, q = lane >> 4;

    const float* gsrc[6];
    int wh_[6], wl_[6];
    #pragma unroll
    for (int c = 0; c < 6; ++c) {
        const int id = c * 256 + tid;
        int row, c4, base;
        if (id < 1024) { row = id >> 3; c4 = id & 7; base = 0;
                         gsrc[c] = X  + (long)(row0 + row) * C + c4 * 4; }
        else { const int j = id - 1024; row = j >> 3; c4 = j & 7; base = 8192;
               gsrc[c] = W1 + (long)(col0 + row) * C + c4 * 4; }
        const int s  = (row ^ (row >> 2)) & 3;
        const int kb = c4 >> 1;
        wh_[c] = base + row * 32 + ((kb ^ s) << 3) + (c4 & 1) * 4;
        wl_[c] = wh_[c] + (base ? 2048 : 4096);
    }
    int aA[4], aB[2];
    #pragma unroll
    for (int f = 0; f < 4; ++f) {
        const int row = wm + f * 16 + lr;
        const int s = (row ^ (row >> 2)) & 3;
        aA[f] = row * 32 + ((q ^ s) << 3);
    }
    #pragma unroll
    for (int g = 0; g < 2; ++g) {
        const int n = wn + g * 16 + lr;
        const int s = (n ^ (n >> 2)) & 3;
        aB[g] = 8192 + n * 32 + ((q ^ s) << 3);
    }

    f32x4 acc0[4][2] = {}, acc1[4][2] = {};
    float4 va[6], vb[6];

#define LOADG(V, KT) { _Pragma("unroll") \
    for (int c = 0; c < 6; ++c) V[c] = *(const float4*)(gsrc[c] + (KT)); }

#define STAGE(V) { _Pragma("unroll") \
    for (int c = 0; c < 6; ++c) { \
        const float4 v = V[c]; f16x4 hv, lv; \
        hv[0] = (_Float16)v.x; lv[0] = (_Float16)((v.x - (float)hv[0]) * 2048.f); \
        hv[1] = (_Float16)v.y; lv[1] = (_Float16)((v.y - (float)hv[1]) * 2048.f); \
        hv[2] = (_Float16)v.z; lv[2] = (_Float16)((v.z - (float)hv[2]) * 2048.f); \
        hv[3] = (_Float16)v.w; lv[3] = (_Float16)((v.w - (float)hv[3]) * 2048.f); \
        *(f16x4*)&smem[wh_[c]] = hv; \
        *(f16x4*)&smem[wl_[c]] = lv; } }

#define COMPUTE() { \
    f16x8 bh0 = *(const f16x8*)&smem[aB[0]]; \
    f16x8 bl0 = *(const f16x8*)&smem[aB[0] + 2048]; \
    f16x8 bh1 = *(const f16x8*)&smem[aB[1]]; \
    f16x8 bl1 = *(const f16x8*)&smem[aB[1] + 2048]; \
    _Pragma("unroll") \
    for (int f = 0; f < 4; ++f) { \
        const f16x8 ah = *(const f16x8*)&smem[aA[f]]; \
        const f16x8 al = *(const f16x8*)&smem[aA[f] + 4096]; \
        acc0[f][0] = __builtin_amdgcn_mfma_f32_16x16x32_f16(ah, bh0, acc0[f][0], 0, 0, 0); \
        acc1[f][0] = __builtin_amdgcn_mfma_f32_16x16x32_f16(ah, bl0, acc1[f][0], 0, 0, 0); \
        acc1[f][0] = __builtin_amdgcn_mfma_f32_16x16x32_f16(al, bh0, acc1[f][0], 0, 0, 0); \
        acc0[f][1] = __builtin_amdgcn_mfma_f32_16x16x32_f16(ah, bh1, acc0[f][1], 0, 0, 0); \
        acc1[f][1] = __builtin_amdgcn_mfma_f32_16x16x32_f16(ah, bl1, acc1[f][1], 0, 0, 0); \
        acc1[f][1] = __builtin_amdgcn_mfma_f32_16x16x32_f16(al, bh1, acc1[f][1], 0, 0, 0); \
    } }

    LOADG(va, 0);
    for (int kt = 0; kt < C; kt += 64) {
        STAGE(va);
        LOADG(vb, kt + 32);
        __syncthreads();
        COMPUTE();
        __syncthreads();
        STAGE(vb);
        if (kt + 64 < C) LOADG(va, kt + 64);
        __syncthreads();
        COMPUTE();
        __syncthreads();
    }
    const int crow = (lane >> 4) * 4, ccol = lane & 15;
    #pragma unroll
    for (int f = 0; f < 4; ++f)
        #pragma unroll
        for (int g = 0; g < 2; ++g)
            #pragma unroll
            for (int r = 0; r < 4; ++r) {
                const int m = row0 + wm + f * 16 + crow + r;
                const int n = col0 + wn + g * 16 + ccol;
                const float v = acc0[f][g][r] + acc1[f][g][r] * INV2048;
                H1[(long)m * RH + n] = v / (1.f + __expf(-v));
            }
#undef LOADG
#undef STAGE
#undef COMPUTE
}

// ---------------- Kernel 3: router2 — logits, top-4, dense transposed weights ----------
__global__ __launch_bounds__(256) void router2_kernel(
    const float* __restrict__ H1, const float* __restrict__ W2,
    float* __restrict__ rwdT) {
    __shared__ __align__(16) float w2t[32 * 292];
    __shared__ int   ids4[32][4];
    __shared__ float vals4[32][4];
    const int tid = threadIdx.x;
    for (int i = tid; i < E * RH; i += 256) {
        const int e = i >> 8, hh = i & 255;
        w2t[e * 292 + (hh >> 5) * 36 + (hh & 31)] = W2[i];
    }
    __syncthreads();
    const int tt = tid >> 3;       // token in block
    const int g  = tid & 7;        // 32-float h-chunk
    const int tok0 = blockIdx.x * 32;
    const int tok = tok0 + tt;
    float4 xr[8];
    const float4* hp4 = (const float4*)(H1 + (long)tok * RH + g * 32);
    #pragma unroll
    for (int q = 0; q < 8; ++q) xr[q] = hp4[q];
    float l[E];
    #pragma unroll
    for (int e = 0; e < E; ++e) {
        const float4* wp = (const float4*)(w2t + e * 292 + g * 36);
        float acc = 0.f;
        #pragma unroll
        for (int q = 0; q < 8; ++q) {
            const float4 w = wp[q];
            acc = fmaf(xr[q].x, w.x, acc); acc = fmaf(xr[q].y, w.y, acc);
            acc = fmaf(xr[q].z, w.z, acc); acc = fmaf(xr[q].w, w.w, acc);
        }
        float v = acc;
        v += __shfl_xor(v, 1);
        v += __shfl_xor(v, 2);
        v += __shfl_xor(v, 4);
        l[e] = v;
    }
    if (g == 0) {
        unsigned chosen = 0u;
        float tv[4]; int ti[4];
        #pragma unroll
        for (int s = 0; s < 4; ++s) {
            float best = -1e30f; int bi = 0;
            #pragma unroll
            for (int e = 0; e < E; ++e) {
                const bool ok = (((chosen >> e) & 1u) == 0u) && (l[e] > best);
                best = ok ? l[e] : best;
                bi   = ok ? e    : bi;
            }
            chosen |= 1u << bi;
            tv[s] = best; ti[s] = bi;
        }
        const float m = tv[0];
        const float ev[4] = {__expf(tv[0] - m), __expf(tv[1] - m),
                             __expf(tv[2] - m), __expf(tv[3] - m)};
        const float inv = 1.f / (ev[0] + ev[1] + ev[2] + ev[3]);
        #pragma unroll
        for (int s = 0; s < 4; ++s) {
            ids4[tt][s]  = ti[s];
            vals4[tt][s] = ev[s] * inv;
        }
    }
    __syncthreads();
    // dense transposed routing weights: rwdT[e][tok] (0 for unselected)
    #pragma unroll
    for (int i = tid; i < 1024; i += 256) {
        const int t = i & 31, ee = i >> 5;
        float v = 0.f;
        #pragma unroll
        for (int s = 0; s < 4; ++s) if (ids4[t][s] == ee) v = vals4[t][s];
        rwdT[(long)ee * TOKENS + tok0 + t] = v;
    }
}

// ---------------- Kernel 4: dense expert MFMA — all (token, expert) pairs --------------
// grid (TOKENS/128, E). Weights as MFMA fragments in 96 VGPRs. No zero pass needed.
// gate/up operand-swapped (C-frag = token-per-lane); hid packed (hh|hl<<16) in
// wave-private swizzled LDS; down reads it back as A-fragments (no barriers).
__global__ __launch_bounds__(256) void expert_dense(
    const float* __restrict__ X, const _Float16* __restrict__ gf,
    const _Float16* __restrict__ uf, const _Float16* __restrict__ dF,
    const float* __restrict__ gammaArr, const float* __restrict__ rwdT,
    float* __restrict__ out) {
    const int e = blockIdx.y;
    const int tok0 = blockIdx.x * 128;
    const int tid  = threadIdx.x;
    const int lane = tid & 63;
    const int wid  = tid >> 6;
    const int lr = lane & 15, q = lane >> 4;
    const float gamg = gammaArr[0], gamu = gammaArr[1], gamd = gammaArr[2];

    __shared__ _Float16 xh[128 * 40];      // 10 KB, padded rows (bank-even)
    __shared__ _Float16 xl[128 * 40];      // 10 KB
    __shared__ unsigned hidb[4][2048];     // 32 KB, wave-private [wid]
    __shared__ float rws[128];

    // ---- weight fragments (per-block constant) ----
    f16x8 gfr[8], ufr[8], dfr[8];
    #pragma unroll
    for (int t8 = 0; t8 < 8; ++t8) {
        const int row = e * 128 + t8 * 16 + lr;
        gfr[t8] = *(const f16x8*)(gf + row * 32 + q * 8);
        ufr[t8] = *(const f16x8*)(uf + row * 32 + q * 8);
    }
    #pragma unroll
    for (int f = 0; f < 8; ++f)
        dfr[f] = *(const f16x8*)(dF + ((e * 8 + f) * 64 + lane) * 8);

    // ---- stage x slice (128 tok x 32 d) as f16 split ----
    {
        const int row = tid >> 1, part = tid & 1;
        const float4* s4 = (const float4*)(X + (size_t)(tok0 + row) * C + e * 32 + part * 16);
        #pragma unroll
        for (int m = 0; m < 4; ++m) {
            const float4 v = s4[m];
            f16x4 hv, lv;
            hv[0] = (_Float16)v.x; lv[0] = (_Float16)((v.x - (float)hv[0]) * 2048.f);
            hv[1] = (_Float16)v.y; lv[1] = (_Float16)((v.y - (float)hv[1]) * 2048.f);
            hv[2] = (_Float16)v.z; lv[2] = (_Float16)((v.z - (float)hv[2]) * 2048.f);
            hv[3] = (_Float16)v.w; lv[3] = (_Float16)((v.w - (float)hv[3]) * 2048.f);
            const int db = part * 16 + m * 4;
            *(f16x4*)&xh[row * 40 + db] = hv;
            *(f16x4*)&xl[row * 40 + db] = lv;
        }
        if (tid < 128) rws[tid] = rwdT[(long)e * TOKENS + tok0 + tid];
    }
    __syncthreads();

    unsigned* hw = hidb[wid];
    const int swz = (lr & 7) << 2;     // XOR on u32-index bits 2-4, b128-safe

    #pragma unroll
    for (int it = 0; it < 2; ++it) {
        const int tokbase = (wid * 2 + it) * 16;
        const f16x8 bxh = *(const f16x8*)&xh[(tokbase + lr) * 40 + q * 8];
        const f16x8 bxl = *(const f16x8*)&xl[(tokbase + lr) * 40 + q * 8];
        // ---- gate/up (swapped: C = [h x tok]) + silu + split-pack to LDS ----
        #pragma unroll
        for (int t8 = 0; t8 < 8; ++t8) {
            const f32x4 z = {0.f, 0.f, 0.f, 0.f};
            f32x4 gh = __builtin_amdgcn_mfma_f32_16x16x32_f16(gfr[t8], bxh, z, 0, 0, 0);
            f32x4 gl = __builtin_amdgcn_mfma_f32_16x16x32_f16(gfr[t8], bxl, z, 0, 0, 0);
            f32x4 uh = __builtin_amdgcn_mfma_f32_16x16x32_f16(ufr[t8], bxh, z, 0, 0, 0);
            f32x4 ul = __builtin_amdgcn_mfma_f32_16x16x32_f16(ufr[t8], bxl, z, 0, 0, 0);
            unsigned pk[4];
            #pragma unroll
            for (int r = 0; r < 4; ++r) {
                const float g = gamg * (gh[r] + gl[r] * INV2048);
                const float u = gamu * (uh[r] + ul[r] * INV2048);
                const float hd = g / (1.f + __expf(-g)) * u;
                union { _Float16 h[2]; unsigned u32; } p;
                p.h[0] = (_Float16)hd;
                p.h[1] = (_Float16)((hd - (float)p.h[0]) * 2048.f);
                pk[r] = p.u32;
            }
            const int h0 = t8 * 16 + q * 4;      // lane holds h0..h0+3 of token lr
            *(uint4*)&hw[lr * 128 + (h0 ^ swz)] = make_uint4(pk[0], pk[1], pk[2], pk[3]);
        }
        // ---- down: A = hid [tok x h], B = dF frags; LDS in-order per wave ----
        f32x4 dh0 = {0,0,0,0}, dl0 = {0,0,0,0}, dh1 = {0,0,0,0}, dl1 = {0,0,0,0};
        #pragma unroll
        for (int kq = 0; kq < 4; ++kq) {
            const int h0d = kq * 32 + q * 8;
            const uint4 wlo = *(const uint4*)&hw[lr * 128 + (h0d ^ swz)];
            const uint4 whi = *(const uint4*)&hw[lr * 128 + ((h0d + 4) ^ swz)];
            union { unsigned u[4]; f16x8 v; } ah, al;
            ah.u[0] = __builtin_amdgcn_perm(wlo.y, wlo.x, 0x05040100u);
            al.u[0] = __builtin_amdgcn_perm(wlo.y, wlo.x, 0x07060302u);
            ah.u[1] = __builtin_amdgcn_perm(wlo.w, wlo.z, 0x05040100u);
            al.u[1] = __builtin_amdgcn_perm(wlo.w, wlo.z, 0x07060302u);
            ah.u[2] = __builtin_amdgcn_perm(whi.y, whi.x, 0x05040100u);
            al.u[2] = __builtin_amdgcn_perm(whi.y, whi.x, 0x07060302u);
            ah.u[3] = __builtin_amdgcn_perm(whi.w, whi.z, 0x05040100u);
            al.u[3] = __builtin_amdgcn_perm(whi.w, whi.z, 0x07060302u);
            dh0 = __builtin_amdgcn_mfma_f32_16x16x32_f16(ah.v, dfr[kq],     dh0, 0, 0, 0);
            dl0 = __builtin_amdgcn_mfma_f32_16x16x32_f16(al.v, dfr[kq],     dl0, 0, 0, 0);
            dh1 = __builtin_amdgcn_mfma_f32_16x16x32_f16(ah.v, dfr[4 + kq], dh1, 0, 0, 0);
            dl1 = __builtin_amdgcn_mfma_f32_16x16x32_f16(al.v, dfr[4 + kq], dl1, 0, 0, 0);
        }
        // ---- epilogue: gamma, routing weight (0 if unselected), dense store ----
        #pragma unroll
        for (int r = 0; r < 4; ++r) {
            const int trow = tokbase + q * 4 + r;
            const float w = rws[trow];
            float* op = out + (size_t)(tok0 + trow) * C + e * 32;
            op[lr]      = gamd * (dh0[r] + dl0[r] * INV2048) * w;
            op[16 + lr] = gamd * (dh1[r] + dl1[r] * INV2048) * w;
        }
    }
}

extern "C" void kernel_launch(void* const* d_in, const int* in_sizes, int n_in,
                              void* d_out, int out_size, void* d_ws, size_t ws_size,
                              hipStream_t stream) {
    const float* x  = (const float*)d_in[0];
    const float* w1 = (const float*)d_in[1];
    const float* w2 = (const float*)d_in[2];
    const float* gw = (const float*)d_in[3];
    const float* uw = (const float*)d_in[4];
    const float* dw = (const float*)d_in[5];
    float* out = (float*)d_out;

    char* ws = (char*)d_ws;
    float*     H1    = (float*)(ws);                              // 16 MB
    size_t off = (size_t)16 << 20;
    _Float16*  gf    = (_Float16*)(ws + off); off += (256 << 10); // 256 KB
    _Float16*  uf    = (_Float16*)(ws + off); off += (256 << 10);
    _Float16*  dF    = (_Float16*)(ws + off); off += (256 << 10);
    float*     rwdT  = (float*)(ws + off);    off += (2 << 20);   // 2 MB
    double*    part  = (double*)(ws + off);   off += 1024;
    float*     gamma = (float*)(ws + off);

    absum_kernel<<<dim3(32, 3), 256, 0, stream>>>(gw, uw, dw, part);
    gamma_kernel<<<1, 64, 0, stream>>>(part, gamma);
    tern_prep<<<192, 256, 0, stream>>>(gw, uw, dw, gamma, gf, uf, dF);
    gemm1_mfma<<<dim3(TOKENS / 128, RH / 64), 256, 0, stream>>>(x, w1, H1);
    router2_kernel<<<TOKENS / 32, 256, 0, stream>>>(H1, w2, rwdT);
    expert_dense<<<dim3(TOKENS / 128, E), 256, 0, stream>>>(x, gf, uf, dF, gamma, rwdT, out);
}